// Round 1
// baseline (15934.418 us; speedup 1.0000x reference)
//
#include <hip/hip_runtime.h>
#include <hip/hip_bf16.h>
#include <math.h>

#define NHID 512
#define NTOK 32000
#define TT 64
#define BB 32

typedef __bf16 bf16x8 __attribute__((ext_vector_type(8)));
typedef float f32x4 __attribute__((ext_vector_type(4)));

__device__ __forceinline__ float sigmf(float x){ return 1.f/(1.f+expf(-x)); }

// ---------------- embedding gather: emb[t,b,d] = table[ids[t,b]][d] ----------------
__global__ void k_embed(const int* __restrict__ ids, const float* __restrict__ tab,
                        float* __restrict__ emb){
  int idx = blockIdx.x*256 + threadIdx.x;        // < 64*32*512 = 1048576
  int row = idx >> 9; int d = idx & 511;
  emb[idx] = tab[(size_t)ids[row]*NHID + d];
}

// ---------------- f32 -> bf16 ----------------
__global__ void k_tobf16(const float* __restrict__ src, __hip_bfloat16* __restrict__ dst, int n){
  int idx = blockIdx.x*256 + threadIdx.x;
  if (idx < n) dst[idx] = __float2bfloat16(src[idx]);
}

__global__ void k_copy(const float* __restrict__ s, float* __restrict__ d){
  int i = blockIdx.x*256 + threadIdx.x; d[i] = s[i];
}

// ---------------- W0 stage: s0 = h + sig(c0)*(tanh(h0)-h), [c0,h0] = [x,h]@W0 -------
// block: 512 thr, covers 32 rows x 32 d-cols (c and h). grid: 16 blocks (512 cols).
__global__ __launch_bounds__(512) void k_w0(const float* __restrict__ embt,
                                            const float* __restrict__ hbt,
                                            const float* __restrict__ W0,
                                            float* __restrict__ ssum){
  __shared__ float w_lds[64][68];
  __shared__ float s_lds[64][36];
  int tid = threadIdx.x;
  int d0 = blockIdx.x * 32;
  int b = tid & 31, dg = tid >> 5;               // dg 0..15, 2 cols each
  float accc0=0.f, accc1=0.f, acch0=0.f, acch1=0.f;
  for (int k0 = 0; k0 < 1024; k0 += 64){
    #pragma unroll
    for (int it = 0; it < 2; ++it){
      int f4 = tid + it*512; int kr = f4 >> 4; int rem = f4 & 15;
      int half = rem >> 3; int c4 = rem & 7;
      float4 v = *(const float4*)&W0[(size_t)(k0+kr)*1024 + half*512 + d0 + c4*4];
      *(float4*)&w_lds[kr][half*32 + c4*4] = v;
    }
    {
      int f4 = tid; int bb = f4 >> 4; int k4 = f4 & 15; int kg = k0 + k4*4;
      const float* src = (kg < 512) ? &embt[bb*512 + kg] : &hbt[bb*512 + (kg-512)];
      float4 v = *(const float4*)src;
      s_lds[k4*4+0][bb] = v.x; s_lds[k4*4+1][bb] = v.y;
      s_lds[k4*4+2][bb] = v.z; s_lds[k4*4+3][bb] = v.w;
    }
    __syncthreads();
    #pragma unroll 8
    for (int kk = 0; kk < 64; ++kk){
      float sv = s_lds[kk][b];
      float2 wc = *(float2*)&w_lds[kk][dg*2];
      float2 wh = *(float2*)&w_lds[kk][32 + dg*2];
      accc0 += sv*wc.x; accc1 += sv*wc.y;
      acch0 += sv*wh.x; acch1 += sv*wh.y;
    }
    __syncthreads();
  }
  int d = d0 + dg*2;
  float hp0 = hbt[b*512 + d], hp1 = hbt[b*512 + d + 1];
  float s0 = hp0 + sigmf(accc0)*(tanhf(acch0) - hp0);
  float s1 = hp1 + sigmf(accc1)*(tanhf(acch1) - hp1);
  ssum[b*512 + d] = s0; ssum[b*512 + d + 1] = s1;
}

// ---------------- edge stage i: for all j>i accumulate s into states_sum[j] ---------
// grid: (16 d-tiles, 7-i targets), block 512.
__global__ __launch_bounds__(512) void k_stage(const float* __restrict__ Ws,
                                               float* __restrict__ ssum, int i){
  int j = i + 1 + blockIdx.y;
  const float* W = Ws + (size_t)(i*8 + j) * 512 * 1024;
  const float* Si = ssum + i*16384;
  float* Sj = ssum + j*16384;
  float inv_i = (i == 0) ? 1.f : (1.f/(float)i);
  int act = (j==1||j==4) ? 1 : ((j==2||j==5) ? 2 : ((j==3||j==6) ? 3 : 0));
  __shared__ float w_lds[64][68];
  __shared__ float s_lds[64][36];
  int tid = threadIdx.x;
  int d0 = blockIdx.x * 32;
  int b = tid & 31, dg = tid >> 5;
  float accc0=0.f, accc1=0.f, acch0=0.f, acch1=0.f;
  for (int k0 = 0; k0 < 512; k0 += 64){
    #pragma unroll
    for (int it = 0; it < 2; ++it){
      int f4 = tid + it*512; int kr = f4 >> 4; int rem = f4 & 15;
      int half = rem >> 3; int c4 = rem & 7;
      float4 v = *(const float4*)&W[(size_t)(k0+kr)*1024 + half*512 + d0 + c4*4];
      *(float4*)&w_lds[kr][half*32 + c4*4] = v;
    }
    {
      int f4 = tid; int bb = f4 >> 4; int k4 = f4 & 15;
      float4 v = *(const float4*)&Si[bb*512 + k0 + k4*4];
      v.x *= inv_i; v.y *= inv_i; v.z *= inv_i; v.w *= inv_i;
      s_lds[k4*4+0][bb] = v.x; s_lds[k4*4+1][bb] = v.y;
      s_lds[k4*4+2][bb] = v.z; s_lds[k4*4+3][bb] = v.w;
    }
    __syncthreads();
    #pragma unroll 8
    for (int kk = 0; kk < 64; ++kk){
      float sv = s_lds[kk][b];
      float2 wc = *(float2*)&w_lds[kk][dg*2];
      float2 wh = *(float2*)&w_lds[kk][32 + dg*2];
      accc0 += sv*wc.x; accc1 += sv*wc.y;
      acch0 += sv*wh.x; acch1 += sv*wh.y;
    }
    __syncthreads();
  }
  int d = d0 + dg*2;
  float sp0 = Si[b*512 + d]   * inv_i;
  float sp1 = Si[b*512 + d+1] * inv_i;
  float a0 = (act==1) ? tanhf(acch0) : ((act==2) ? fmaxf(acch0,0.f) : ((act==3) ? sigmf(acch0) : acch0));
  float a1 = (act==1) ? tanhf(acch1) : ((act==2) ? fmaxf(acch1,0.f) : ((act==3) ? sigmf(acch1) : acch1));
  float s0v = sp0 + sigmf(accc0)*(a0 - sp0);
  float s1v = sp1 + sigmf(accc1)*(a1 - sp1);
  if (i == 0){ Sj[b*512 + d] = s0v; Sj[b*512 + d + 1] = s1v; }
  else       { Sj[b*512 + d] += s0v; Sj[b*512 + d + 1] += s1v; }
}

// ---------------- mean of leaf nodes -> next h (f32) + bf16 row for decoder --------
__global__ void k_mean(const float* __restrict__ ssum, float* __restrict__ hnext,
                       __hip_bfloat16* __restrict__ abf){
  int idx = blockIdx.x*256 + threadIdx.x;        // < 16384
  float v = 0.f;
  #pragma unroll
  for (int j = 1; j < 8; ++j) v += ssum[j*16384 + idx] * (1.f/(float)j);
  float h = v * (1.f/7.f);
  hnext[idx] = h;
  abf[idx] = __float2bfloat16(h);
}

// ---------------- decoder GEMM: out[m,n] = sum_k A[m,k]*Bt[n,k] + bias[n] ----------
// bf16 MFMA 16x16x32, 128x128 tile, 4 waves (2x2), wave tile 64x64 (4x4 frags).
__global__ __launch_bounds__(256) void k_gemm(const __hip_bfloat16* __restrict__ A,
                                              const __hip_bfloat16* __restrict__ Bt,
                                              const float* __restrict__ bias,
                                              float* __restrict__ out){
  __shared__ __align__(16) unsigned short A_lds[128*72];
  __shared__ __align__(16) unsigned short B_lds[128*72];
  int tid = threadIdx.x;
  int n0 = blockIdx.x * 128, m0 = blockIdx.y * 128;
  int lane = tid & 63, wv = tid >> 6, wr = wv >> 1, wc = wv & 1;
  f32x4 acc[4][4];
  #pragma unroll
  for (int a = 0; a < 4; ++a)
    #pragma unroll
    for (int bq = 0; bq < 4; ++bq) acc[a][bq] = (f32x4){0.f,0.f,0.f,0.f};

  for (int k0 = 0; k0 < 512; k0 += 64){
    #pragma unroll
    for (int it = 0; it < 4; ++it){
      int c = tid + it*256; int row = c >> 3, c8 = c & 7;
      *(int4*)&A_lds[row*72 + c8*8] = *(const int4*)&A[(size_t)(m0+row)*512 + k0 + c8*8];
      *(int4*)&B_lds[row*72 + c8*8] = *(const int4*)&Bt[(size_t)(n0+row)*512 + k0 + c8*8];
    }
    __syncthreads();
    #pragma unroll
    for (int kk = 0; kk < 64; kk += 32){
      bf16x8 av[4], bv[4];
      #pragma unroll
      for (int f = 0; f < 4; ++f){
        av[f] = *(const bf16x8*)&A_lds[(wr*64 + f*16 + (lane&15))*72 + kk + (lane>>4)*8];
        bv[f] = *(const bf16x8*)&B_lds[(wc*64 + f*16 + (lane&15))*72 + kk + (lane>>4)*8];
      }
      #pragma unroll
      for (int fm = 0; fm < 4; ++fm)
        #pragma unroll
        for (int fn = 0; fn < 4; ++fn)
          acc[fm][fn] = __builtin_amdgcn_mfma_f32_16x16x32_bf16(av[fm], bv[fn], acc[fm][fn], 0, 0, 0);
    }
    __syncthreads();
  }
  #pragma unroll
  for (int fm = 0; fm < 4; ++fm){
    int mbase = m0 + wr*64 + fm*16 + ((lane>>4)<<2);
    #pragma unroll
    for (int fn = 0; fn < 4; ++fn){
      int n = n0 + wc*64 + fn*16 + (lane & 15);
      float bs = bias[n];
      #pragma unroll
      for (int r = 0; r < 4; ++r)
        out[(size_t)(mbase+r)*NTOK + n] = acc[fm][fn][r] + bs;
    }
  }
}

// ---------------- in-place log_softmax per row of 32000 ----------------
__global__ __launch_bounds__(256) void k_lsm(float* __restrict__ out){
  __shared__ float red[256];
  int row = blockIdx.x, tid = threadIdx.x;
  float* p = out + (size_t)row * NTOK;
  float m = -INFINITY;
  for (int i = tid; i < NTOK; i += 256) m = fmaxf(m, p[i]);
  red[tid] = m; __syncthreads();
  for (int s = 128; s > 0; s >>= 1){ if (tid < s) red[tid] = fmaxf(red[tid], red[tid+s]); __syncthreads(); }
  float rowmax = red[0]; __syncthreads();
  float sum = 0.f;
  for (int i = tid; i < NTOK; i += 256) sum += expf(p[i] - rowmax);
  red[tid] = sum; __syncthreads();
  for (int s = 128; s > 0; s >>= 1){ if (tid < s) red[tid] += red[tid+s]; __syncthreads(); }
  float ls = logf(red[0]);
  for (int i = tid; i < NTOK; i += 256) p[i] = p[i] - rowmax - ls;
}

__global__ void k_lasth(const float* __restrict__ h, float* __restrict__ o){
  int i = blockIdx.x*256 + threadIdx.x; o[i] = h[i];
}

extern "C" void kernel_launch(void* const* d_in, const int* in_sizes, int n_in,
                              void* d_out, int out_size, void* d_ws, size_t ws_size,
                              hipStream_t stream) {
  const int*   ids     = (const int*)  d_in[0];
  const float* hidden0 = (const float*)d_in[1];
  const float* table   = (const float*)d_in[2];
  const float* W0      = (const float*)d_in[3];
  const float* Ws      = (const float*)d_in[4];
  const float* bias    = (const float*)d_in[5];
  float* out = (float*)d_out;

  float* emb  = (float*)d_ws;                      // 1,048,576 f
  float* hbuf = emb  + 1048576;                    // 65*16384 = 1,064,960 f
  float* ssum = hbuf + 1064960;                    // 8*16384  = 131,072 f
  __hip_bfloat16* Abf = (__hip_bfloat16*)(ssum + 131072);   // 2048*512
  __hip_bfloat16* Tbf = Abf + 1048576;                      // 32000*512

  k_embed <<<4096,  256, 0, stream>>>(ids, table, emb);
  k_tobf16<<<64000, 256, 0, stream>>>(table, Tbf, NTOK*NHID);
  k_copy  <<<64,    256, 0, stream>>>(hidden0, hbuf);

  for (int t = 0; t < TT; ++t){
    k_w0<<<16, 512, 0, stream>>>(emb + t*16384, hbuf + t*16384, W0, ssum);
    for (int i = 0; i < 7; ++i)
      k_stage<<<dim3(16, 7 - i), 512, 0, stream>>>(Ws, ssum, i);
    k_mean<<<64, 256, 0, stream>>>(ssum, hbuf + (t+1)*16384, Abf + t*16384);
  }

  k_gemm <<<dim3(250, 16), 256, 0, stream>>>(Abf, Tbf, bias, out);
  k_lsm  <<<2048, 256, 0, stream>>>(out);
  k_lasth<<<64, 256, 0, stream>>>(hbuf + 64*16384, out + (size_t)2048*NTOK);
}

// Round 2
// 8848.581 us; speedup vs baseline: 1.8008x; 1.8008x over previous
//
#include <hip/hip_runtime.h>
#include <hip/hip_fp16.h>
#include <math.h>

#define NTOK 32000

typedef _Float16 half8 __attribute__((ext_vector_type(8)));
typedef _Float16 half4v __attribute__((ext_vector_type(4)));
typedef float f32x4 __attribute__((ext_vector_type(4)));

__device__ __forceinline__ float sigmf(float x){ return 1.f/(1.f+__expf(-x)); }

__device__ __constant__ int E_I[28] = {0,0,0,0,0,0,0, 1,1,1,1,1,1, 2,2,2,2,2, 3,3,3,3, 4,4,4, 5,5, 6};
__device__ __constant__ int E_J[28] = {1,2,3,4,5,6,7, 2,3,4,5,6,7, 3,4,5,6,7, 4,5,6,7, 5,6,7, 6,7, 7};
__device__ __constant__ int ACTC[8] = {0,1,2,3,1,2,3,0};

__device__ __forceinline__ half8 pack8(float4 a, float4 b){
  half8 h;
  h[0]=(_Float16)a.x; h[1]=(_Float16)a.y; h[2]=(_Float16)a.z; h[3]=(_Float16)a.w;
  h[4]=(_Float16)b.x; h[5]=(_Float16)b.y; h[6]=(_Float16)b.z; h[7]=(_Float16)b.w;
  return h;
}

// 3-level (8-8-8) device barrier over 512 blocks; counters monotonic, memset to 0 per launch.
__device__ __forceinline__ void gbar(int* ctl, int ph){
  __syncthreads();
  if (threadIdx.x == 0){
    __builtin_amdgcn_fence(__ATOMIC_RELEASE, "agent");
    int g = blockIdx.x & 63, s = g & 7;
    int* c0 = ctl + g*32;       int* g0 = ctl + (64+g)*32;
    int* c1 = ctl + (128+s)*32; int* g1 = ctl + (136+s)*32;
    int* c2 = ctl + 144*32;     int* g2 = ctl + 145*32;
    int tgt = ph*8;
    if (__hip_atomic_fetch_add(c0,1,__ATOMIC_RELAXED,__HIP_MEMORY_SCOPE_AGENT)+1 == tgt){
      if (__hip_atomic_fetch_add(c1,1,__ATOMIC_RELAXED,__HIP_MEMORY_SCOPE_AGENT)+1 == tgt){
        if (__hip_atomic_fetch_add(c2,1,__ATOMIC_RELAXED,__HIP_MEMORY_SCOPE_AGENT)+1 == tgt){
          __hip_atomic_store(g2,ph,__ATOMIC_RELAXED,__HIP_MEMORY_SCOPE_AGENT);
        } else { while(__hip_atomic_load(g2,__ATOMIC_RELAXED,__HIP_MEMORY_SCOPE_AGENT) < ph) __builtin_amdgcn_s_sleep(1); }
        __hip_atomic_store(g1,ph,__ATOMIC_RELAXED,__HIP_MEMORY_SCOPE_AGENT);
      } else { while(__hip_atomic_load(g1,__ATOMIC_RELAXED,__HIP_MEMORY_SCOPE_AGENT) < ph) __builtin_amdgcn_s_sleep(1); }
      __hip_atomic_store(g0,ph,__ATOMIC_RELAXED,__HIP_MEMORY_SCOPE_AGENT);
    } else { while(__hip_atomic_load(g0,__ATOMIC_RELAXED,__HIP_MEMORY_SCOPE_AGENT) < ph) __builtin_amdgcn_s_sleep(1); }
    __builtin_amdgcn_fence(__ATOMIC_ACQUIRE, "agent");
  }
  __syncthreads();
}

// Persistent scan kernel. 512 blocks x 256 thr, 64KB LDS each (weights resident in fp16).
// Blocks 0..63:  W0 job, 8 d-cols each ([16][1024] fp16 weights = 32KB + 32KB h-staging).
// Blocks 64..511: edge job, edge ei = (blk-64)>>4, 32 d-cols ([64][512] fp16 = 64KB).
__global__ __launch_bounds__(256, 2) void k_scan(
    const int* __restrict__ ids, const float* __restrict__ h0f,
    const float* __restrict__ tab, const float* __restrict__ W0g,
    const float* __restrict__ Wsg, int* __restrict__ ctl,
    float* __restrict__ sum32, _Float16* __restrict__ emb16,
    _Float16* __restrict__ A16, _Float16* __restrict__ T16,
    float* __restrict__ outLH)
{
  __shared__ unsigned short smem[32768];   // 64KB
  const int tid = threadIdx.x, blk = blockIdx.x;
  const int lane = tid & 63, wv = tid >> 6;
  int ph = 0;

  // ---------- prologue ----------
  {  // emb_table -> fp16 (decoder B operand): 2,048,000 half8 groups
    const float4* t4 = (const float4*)tab;
    for (int it = 0; it < 16; ++it){
      int idx = blk*4096 + it*256 + tid;
      if (idx < 2048000){
        float4 a = t4[idx*2], b = t4[idx*2+1];
        *(half8*)&T16[(size_t)idx*8] = pack8(a,b);
      }
    }
  }
  {  // embedding gather -> fp16: 131072 half8 groups (exact)
    int idx = blk*256 + tid;
    int row = idx >> 6; int koff = (idx & 63)*8;
    const float4* src = (const float4*)(tab + (size_t)ids[row]*512 + koff);
    *(half8*)&emb16[(size_t)idx*8] = pack8(src[0], src[1]);
  }
  int d0, ei = 0, jn = 0, in_ = 0;
  if (blk < 64){
    d0 = blk*8;   // weights [16 n][1024 k]: n<8 -> c col d0+n, n>=8 -> h col 512+d0+n-8
    for (int it = 0; it < 8; ++it){
      int c = it*256 + tid;
      int n = c & 15, k0 = (c >> 4)*8;
      int gcol = (n < 8) ? (d0 + n) : (512 + d0 + n - 8);
      half8 h;
      #pragma unroll
      for (int m = 0; m < 8; ++m) h[m] = (_Float16)W0g[(size_t)(k0+m)*1024 + gcol];
      *(half8*)&smem[n*1024 + (k0 ^ ((n&7)<<3))] = h;
    }
  } else {
    int p = blk - 64; ei = p >> 4; int q = p & 15; d0 = q*32;
    in_ = E_I[ei]; jn = E_J[ei];
    float wscale = (in_ > 0) ? 1.f/(float)in_ : 1.f;   // fold 1/count into weights
    const float* W = Wsg + (size_t)(in_*8 + jn)*524288;
    for (int it = 0; it < 16; ++it){
      int c = it*256 + tid;
      int n = c & 63, k0 = (c >> 6)*8;
      int gcol = (n < 32) ? (d0 + n) : (512 + d0 + n - 32);
      half8 h;
      #pragma unroll
      for (int m = 0; m < 8; ++m) h[m] = (_Float16)(W[(size_t)(k0+m)*1024 + gcol] * wscale);
      *(half8*)&smem[n*512 + (k0 ^ ((n&7)<<3))] = h;
    }
  }
  gbar(ctl, ++ph);

  // ---------- scan ----------
  for (int t = 0; t < 64; ++t){
    // ----- W0 phase: mean(prev sums) -> h staged in LDS; [x|h]@W0 -> s0 -----
    if (blk < 64){
      for (int e4 = tid; e4 < 4096; e4 += 256){
        int b = e4 >> 7, d = (e4 & 127)*4;
        float4 h4;
        if (t == 0) h4 = ((const float4*)h0f)[e4];
        else {
          h4.x = 0.f; h4.y = 0.f; h4.z = 0.f; h4.w = 0.f;
          #pragma unroll
          for (int j = 1; j < 8; ++j){
            float4 v = ((const float4*)(sum32 + j*16384))[e4];
            float sc = 1.f/(7.f*(float)j);
            h4.x += v.x*sc; h4.y += v.y*sc; h4.z += v.z*sc; h4.w += v.w*sc;
          }
        }
        half4v hv; hv[0]=(_Float16)h4.x; hv[1]=(_Float16)h4.y; hv[2]=(_Float16)h4.z; hv[3]=(_Float16)h4.w;
        *(half4v*)&smem[16384 + b*512 + (d ^ ((b&7)<<3))] = hv;
        if (t > 0 && (d >> 3) == blk)
          *(half4v*)&A16[(size_t)((t-1)*32 + b)*512 + d] = hv;
      }
      __syncthreads();
      if (wv < 2){
        int mt = wv;
        f32x4 acc = {0.f,0.f,0.f,0.f};
        int bidx = mt*16 + (lane & 15);
        int n = lane & 15;
        for (int kk = 0; kk < 32; ++kk){
          int kc = kk*32 + (lane >> 4)*8;
          half8 af;
          if (kc < 512) af = *(const half8*)&emb16[(size_t)t*16384 + bidx*512 + kc];
          else          af = *(const half8*)&smem[16384 + bidx*512 + ((kc-512) ^ ((bidx&7)<<3))];
          half8 bf = *(const half8*)&smem[n*1024 + (kc ^ ((n&7)<<3))];
          acc = __builtin_amdgcn_mfma_f32_16x16x32_f16(af, bf, acc, 0, 0, 0);
        }
        #pragma unroll
        for (int r = 0; r < 4; ++r){
          float other = __shfl_xor(acc[r], 8, 64);   // h-half lives 8 lanes over
          if (n < 8){
            int b = mt*16 + (lane >> 4)*4 + r;
            int d = d0 + n;
            float hp = (float)(((const _Float16*)smem)[16384 + b*512 + (d ^ ((b&7)<<3))]);
            float s0 = hp + sigmf(acc[r]) * (tanhf(other) - hp);
            sum32[b*512 + d] = s0;
          }
        }
      }
    }
    gbar(ctl, ++ph);

    // ----- edge stages 0..6 -----
    for (int i = 0; i < 7; ++i){
      if (blk >= 64 && in_ == i){
        const float* A = sum32 + i*16384;
        int mt = wv >> 1, ch = wv & 1;
        f32x4 accc = {0.f,0.f,0.f,0.f}, acch = {0.f,0.f,0.f,0.f};
        int bidx = mt*16 + (lane & 15);
        int nc = ch*16 + (lane & 15);
        int nh = nc + 32;
        for (int kk = 0; kk < 16; ++kk){
          int kc = kk*32 + (lane >> 4)*8;
          float4 a0 = *(const float4*)&A[bidx*512 + kc];
          float4 a1 = *(const float4*)&A[bidx*512 + kc + 4];
          half8 af = pack8(a0, a1);
          half8 bc = *(const half8*)&smem[nc*512 + (kc ^ ((nc&7)<<3))];
          half8 bh = *(const half8*)&smem[nh*512 + (kc ^ ((nh&7)<<3))];
          accc = __builtin_amdgcn_mfma_f32_16x16x32_f16(af, bc, accc, 0, 0, 0);
          acch = __builtin_amdgcn_mfma_f32_16x16x32_f16(af, bh, acch, 0, 0, 0);
        }
        float invi = (i > 0) ? 1.f/(float)i : 1.f;
        float* SJ = sum32 + jn*16384;
        int d = d0 + ch*16 + (lane & 15);
        int actc = ACTC[jn];
        #pragma unroll
        for (int r = 0; r < 4; ++r){
          int b = mt*16 + (lane >> 4)*4 + r;
          float sp = A[b*512 + d] * invi;
          float hh = acch[r];
          float a = (actc==1) ? tanhf(hh) : (actc==2) ? fmaxf(hh,0.f) : (actc==3) ? sigmf(hh) : hh;
          float s = sp + sigmf(accc[r]) * (a - sp);
          if (i == 0) SJ[b*512 + d] = s;
          else        SJ[b*512 + d] += s;
        }
      }
      gbar(ctl, ++ph);
    }
  }

  // ---------- epilogue: h_64 -> last_h (fp32) + A16 rows 2016..2047 ----------
  if (blk < 64){
    for (int e4 = tid; e4 < 4096; e4 += 256){
      int b = e4 >> 7, d = (e4 & 127)*4;
      if ((d >> 3) != blk) continue;
      float4 h4; h4.x = 0.f; h4.y = 0.f; h4.z = 0.f; h4.w = 0.f;
      #pragma unroll
      for (int j = 1; j < 8; ++j){
        float4 v = ((const float4*)(sum32 + j*16384))[e4];
        float sc = 1.f/(7.f*(float)j);
        h4.x += v.x*sc; h4.y += v.y*sc; h4.z += v.z*sc; h4.w += v.w*sc;
      }
      ((float4*)outLH)[e4] = h4;
      half4v hv; hv[0]=(_Float16)h4.x; hv[1]=(_Float16)h4.y; hv[2]=(_Float16)h4.z; hv[3]=(_Float16)h4.w;
      *(half4v*)&A16[(size_t)(2016 + b)*512 + d] = hv;
    }
  }
}

// ---------------- decoder GEMM: out[m,n] = sum_k A[m,k]*Bt[n,k] + bias[n], fp16 MFMA ----
__global__ __launch_bounds__(256) void k_gemm(const _Float16* __restrict__ A,
                                              const _Float16* __restrict__ Bt,
                                              const float* __restrict__ bias,
                                              float* __restrict__ out){
  __shared__ __align__(16) unsigned short A_lds[128*72];
  __shared__ __align__(16) unsigned short B_lds[128*72];
  int tid = threadIdx.x;
  int n0 = blockIdx.x * 128, m0 = blockIdx.y * 128;
  int lane = tid & 63, wvv = tid >> 6, wr = wvv >> 1, wc = wvv & 1;
  f32x4 acc[4][4];
  #pragma unroll
  for (int a = 0; a < 4; ++a)
    #pragma unroll
    for (int bq = 0; bq < 4; ++bq) acc[a][bq] = (f32x4){0.f,0.f,0.f,0.f};

  for (int k0 = 0; k0 < 512; k0 += 64){
    #pragma unroll
    for (int it = 0; it < 4; ++it){
      int c = tid + it*256; int row = c >> 3, c8 = c & 7;
      *(int4*)&A_lds[row*72 + c8*8] = *(const int4*)&A[(size_t)(m0+row)*512 + k0 + c8*8];
      *(int4*)&B_lds[row*72 + c8*8] = *(const int4*)&Bt[(size_t)(n0+row)*512 + k0 + c8*8];
    }
    __syncthreads();
    #pragma unroll
    for (int kk = 0; kk < 64; kk += 32){
      half8 av[4], bv[4];
      #pragma unroll
      for (int f = 0; f < 4; ++f){
        av[f] = *(const half8*)&A_lds[(wr*64 + f*16 + (lane&15))*72 + kk + (lane>>4)*8];
        bv[f] = *(const half8*)&B_lds[(wc*64 + f*16 + (lane&15))*72 + kk + (lane>>4)*8];
      }
      #pragma unroll
      for (int fm = 0; fm < 4; ++fm)
        #pragma unroll
        for (int fn = 0; fn < 4; ++fn)
          acc[fm][fn] = __builtin_amdgcn_mfma_f32_16x16x32_f16(av[fm], bv[fn], acc[fm][fn], 0, 0, 0);
    }
    __syncthreads();
  }
  #pragma unroll
  for (int fm = 0; fm < 4; ++fm){
    int mbase = m0 + wr*64 + fm*16 + ((lane>>4)<<2);
    #pragma unroll
    for (int fn = 0; fn < 4; ++fn){
      int n = n0 + wc*64 + fn*16 + (lane & 15);
      float bs = bias[n];
      #pragma unroll
      for (int r = 0; r < 4; ++r)
        out[(size_t)(mbase+r)*NTOK + n] = acc[fm][fn][r] + bs;
    }
  }
}

// ---------------- online log_softmax per row of 32000 (2 reads + 1 write) -------------
__global__ __launch_bounds__(256) void k_lsm(float* __restrict__ out){
  __shared__ float redm[8], reds[8];
  int row = blockIdx.x, tid = threadIdx.x;
  float* p = out + (size_t)row * NTOK;
  float4* p4 = (float4*)p;
  float m = -INFINITY, s = 0.f;
  for (int i = tid; i < 8000; i += 256){
    float4 v = p4[i];
    float vm = fmaxf(fmaxf(v.x,v.y), fmaxf(v.z,v.w));
    if (vm > m){ s *= __expf(m - vm); m = vm; }
    s += __expf(v.x-m)+__expf(v.y-m)+__expf(v.z-m)+__expf(v.w-m);
  }
  #pragma unroll
  for (int off = 32; off > 0; off >>= 1){
    float om = __shfl_down(m, off, 64);
    float os = __shfl_down(s, off, 64);
    float nm = fmaxf(m, om);
    s = s*__expf(m-nm) + os*__expf(om-nm);
    m = nm;
  }
  int wv = tid >> 6;
  if ((tid & 63) == 0){ redm[wv] = m; reds[wv] = s; }
  __syncthreads();
  if (tid == 0){
    m = redm[0]; s = reds[0];
    for (int w = 1; w < 4; ++w){
      float om = redm[w], os = reds[w];
      float nm = fmaxf(m, om);
      s = s*__expf(m-nm) + os*__expf(om-nm);
      m = nm;
    }
    redm[0] = m; reds[0] = logf(s);
  }
  __syncthreads();
  float L = redm[0] + reds[0];
  for (int i = tid; i < 8000; i += 256){
    float4 v = p4[i];
    v.x -= L; v.y -= L; v.z -= L; v.w -= L;
    p4[i] = v;
  }
}

extern "C" void kernel_launch(void* const* d_in, const int* in_sizes, int n_in,
                              void* d_out, int out_size, void* d_ws, size_t ws_size,
                              hipStream_t stream) {
  const int*   ids   = (const int*)  d_in[0];
  const float* h0f   = (const float*)d_in[1];
  const float* tab   = (const float*)d_in[2];
  const float* W0g   = (const float*)d_in[3];
  const float* Wsg   = (const float*)d_in[4];
  const float* bias  = (const float*)d_in[5];
  float* out = (float*)d_out;

  char* w = (char*)d_ws;
  int*       ctl   = (int*)w;                                          // 32KB (memset 0)
  float*     sum32 = (float*)(w + 32768);                              // 512KB
  _Float16*  emb16 = (_Float16*)(w + 32768 + 524288);                  // 2MB
  _Float16*  A16   = (_Float16*)(w + 32768 + 524288 + 2097152);        // 2MB
  _Float16*  T16   = (_Float16*)(w + 32768 + 524288 + 2097152 + 2097152); // 32MB

  hipMemsetAsync(ctl, 0, 32768, stream);
  k_scan<<<512, 256, 0, stream>>>(ids, h0f, tab, W0g, Wsg, ctl, sum32, emb16, A16, T16,
                                  out + (size_t)2048*NTOK);
  k_gemm<<<dim3(250,16), 256, 0, stream>>>(A16, T16, bias, out);
  k_lsm<<<2048, 256, 0, stream>>>(out);
}

// Round 3
// 6304.350 us; speedup vs baseline: 2.5275x; 1.4036x over previous
//
#include <hip/hip_runtime.h>
#include <hip/hip_fp16.h>
#include <math.h>

#define NTOK 32000

typedef _Float16 half8 __attribute__((ext_vector_type(8)));
typedef _Float16 half4v __attribute__((ext_vector_type(4)));
typedef float f32x4 __attribute__((ext_vector_type(4)));
typedef unsigned long long ull;

__device__ __forceinline__ float sigmf(float x){ return 1.f/(1.f+__expf(-x)); }

__device__ __constant__ int E_I[28] = {0,0,0,0,0,0,0, 1,1,1,1,1,1, 2,2,2,2,2, 3,3,3,3, 4,4,4, 5,5, 6};
__device__ __constant__ int E_J[28] = {1,2,3,4,5,6,7, 2,3,4,5,6,7, 3,4,5,6,7, 4,5,6,7, 5,6,7, 6,7, 7};
__device__ __constant__ int ACTC[8] = {0,1,2,3,1,2,3,0};

__device__ __forceinline__ half8 pack8(float4 a, float4 b){
  half8 h;
  h[0]=(_Float16)a.x; h[1]=(_Float16)a.y; h[2]=(_Float16)a.z; h[3]=(_Float16)a.w;
  h[4]=(_Float16)b.x; h[5]=(_Float16)b.y; h[6]=(_Float16)b.z; h[7]=(_Float16)b.w;
  return h;
}

// ---- coherent (agent-scope, L3) data movement: no fences, write-through ----
__device__ __forceinline__ float2 cload2(const float* p){
  ull q = __hip_atomic_load((ull*)p, __ATOMIC_RELAXED, __HIP_MEMORY_SCOPE_AGENT);
  union { ull u; float2 f; } x; x.u = q; return x.f;
}
__device__ __forceinline__ void cstore2(float* p, float a, float b){
  union { float f[2]; ull u; } x; x.f[0]=a; x.f[1]=b;
  __hip_atomic_store((ull*)p, x.u, __ATOMIC_RELAXED, __HIP_MEMORY_SCOPE_AGENT);
}
__device__ __forceinline__ float cload1(const float* p){
  return __hip_atomic_load((float*)p, __ATOMIC_RELAXED, __HIP_MEMORY_SCOPE_AGENT);
}
__device__ __forceinline__ void cstore1(float* p, float v){
  __hip_atomic_store(p, v, __ATOMIC_RELAXED, __HIP_MEMORY_SCOPE_AGENT);
}
__device__ __forceinline__ void cadd(float* p, float v){
  __hip_atomic_fetch_add(p, v, __ATOMIC_RELAXED, __HIP_MEMORY_SCOPE_AGENT);
}
__device__ __forceinline__ void cstoreu(ull* p, ull v){
  __hip_atomic_store(p, v, __ATOMIC_RELAXED, __HIP_MEMORY_SCOPE_AGENT);
}
__device__ __forceinline__ void bump(int* c){
  __hip_atomic_fetch_add(c, 1, __ATOMIC_RELAXED, __HIP_MEMORY_SCOPE_AGENT);
}
__device__ __forceinline__ void waitge(int* c, int tgt){
  while (__hip_atomic_load(c, __ATOMIC_RELAXED, __HIP_MEMORY_SCOPE_AGENT) < tgt)
    __builtin_amdgcn_s_sleep(1);
}
__device__ __forceinline__ void drain(){
  asm volatile("s_waitcnt vmcnt(0)" ::: "memory");
}

// Persistent scan kernel. 512 blocks x 256 thr, 64KB LDS (weights resident fp16).
// Blocks 0..63:  W0 job (d0 = blk*8). Blocks 64..511: edge job ei=(blk-64)>>4, d0=(blk&15... q)*32.
// Sync: monotonic per-node ready[] + init[] flags; data via L3-coherent ops; states double-buffered.
__global__ __launch_bounds__(256, 2) void k_scan(
    const int* __restrict__ ids, const float* __restrict__ h0f,
    const float* __restrict__ tab, const float* __restrict__ W0g,
    const float* __restrict__ Wsg, int* __restrict__ ctl,
    float* __restrict__ hacc, float* __restrict__ sumb,
    _Float16* __restrict__ emb16, _Float16* __restrict__ A16,
    _Float16* __restrict__ T16, float* __restrict__ outLH)
{
  __shared__ unsigned short smem[32768];   // 64KB
  const int tid = threadIdx.x, blk = blockIdx.x;
  const int lane = tid & 63, wv = tid >> 6;
  int* ready = ctl;             // ready[j] at ctl[j*32]
  int* initc = ctl + 8*32;      // init[j]  at ctl[(8+j)*32]
  int* prg   = ctl + 16*32;     // prologue counter

  // ---------- prologue ----------
  {  // emb_table -> fp16 decoder operand (plain stores; consumed by next kernel)
    const float4* t4 = (const float4*)tab;
    for (int it = 0; it < 16; ++it){
      int idx = blk*4096 + it*256 + tid;
      if (idx < 2048000){
        float4 a = t4[idx*2], b = t4[idx*2+1];
        *(half8*)&T16[(size_t)idx*8] = pack8(a,b);
      }
    }
  }
  {  // embedding gather -> fp16, coherent stores (read by W0 blocks in-kernel)
    int idx = blk*256 + tid;
    int row = idx >> 6; int koff = (idx & 63)*8;
    const float4* src = (const float4*)(tab + (size_t)ids[row]*512 + koff);
    union { half8 h; ull u[2]; } cv; cv.h = pack8(src[0], src[1]);
    cstoreu((ull*)&emb16[(size_t)idx*8], cv.u[0]);
    cstoreu(((ull*)&emb16[(size_t)idx*8]) + 1, cv.u[1]);
  }
  int d0 = 0, ei = 0, q = 0, jn = 0, in_ = 0;
  if (blk < 64){
    d0 = blk*8;   // W0 weights [16 n][1024 k] fp16 = 32KB
    for (int it = 0; it < 8; ++it){
      int c = it*256 + tid;
      int n = c & 15, k0 = (c >> 4)*8;
      int gcol = (n < 8) ? (d0 + n) : (512 + d0 + n - 8);
      half8 h;
      #pragma unroll
      for (int m = 0; m < 8; ++m) h[m] = (_Float16)W0g[(size_t)(k0+m)*1024 + gcol];
      *(half8*)&smem[n*1024 + (k0 ^ ((n&7)<<3))] = h;
    }
  } else {
    int p = blk - 64; ei = p >> 4; q = p & 15; d0 = q*32;
    in_ = E_I[ei]; jn = E_J[ei];
    float wscale = (in_ > 0) ? 1.f/(float)in_ : 1.f;   // fold 1/count into weights
    const float* W = Wsg + (size_t)(in_*8 + jn)*524288;
    for (int it = 0; it < 16; ++it){
      int c = it*256 + tid;
      int n = c & 63, k0 = (c >> 6)*8;
      int gcol = (n < 32) ? (d0 + n) : (512 + d0 + n - 32);
      half8 h;
      #pragma unroll
      for (int m = 0; m < 8; ++m) h[m] = (_Float16)(W[(size_t)(k0+m)*1024 + gcol] * wscale);
      *(half8*)&smem[n*512 + (k0 ^ ((n&7)<<3))] = h;
    }
  }
  drain();
  __syncthreads();
  if (tid == 0) bump(prg);

  // ---------- scan ----------
  if (blk < 64){
    // ================= W0 blocks =================
    waitge(prg, 512);
    for (int t = 0; t < 64; ++t){
      if (t > 0) waitge(ready + 7*32, 112*t);   // step t-1 fully done (implies all nodes+hacc)
      const float* hr = hacc + ((t+1)&1)*16384; // = (t-1)&1
      for (int e4 = tid; e4 < 4096; e4 += 256){
        int b = e4 >> 7, d = (e4 & 127)*4;
        float4 h4;
        if (t == 0) h4 = ((const float4*)h0f)[e4];
        else {
          float2 u = cload2(&hr[b*512 + d]);
          float2 v = cload2(&hr[b*512 + d + 2]);
          h4.x = u.x; h4.y = u.y; h4.z = v.x; h4.w = v.y;
        }
        half4v hv; hv[0]=(_Float16)h4.x; hv[1]=(_Float16)h4.y; hv[2]=(_Float16)h4.z; hv[3]=(_Float16)h4.w;
        *(half4v*)&smem[16384 + b*512 + (d ^ ((b&7)<<3))] = hv;
        if (t > 0 && (d >> 3) == blk)
          *(half4v*)&A16[(size_t)((t-1)*32 + b)*512 + d] = hv;
      }
      __syncthreads();
      if (wv < 2){
        int mt = wv;
        f32x4 acc = {0.f,0.f,0.f,0.f};
        int bidx = mt*16 + (lane & 15);
        int n = lane & 15;
        for (int kk = 0; kk < 32; ++kk){
          int kc = kk*32 + (lane >> 4)*8;
          half8 af;
          if (kc < 512) af = *(const half8*)&emb16[(size_t)t*16384 + bidx*512 + kc];
          else          af = *(const half8*)&smem[16384 + bidx*512 + ((kc-512) ^ ((bidx&7)<<3))];
          half8 bf = *(const half8*)&smem[n*1024 + (kc ^ ((n&7)<<3))];
          acc = __builtin_amdgcn_mfma_f32_16x16x32_f16(af, bf, acc, 0, 0, 0);
        }
        float* S0 = sumb + (t&1)*131072;
        #pragma unroll
        for (int r = 0; r < 4; ++r){
          float other = __shfl_xor(acc[r], 8, 64);   // h-half lives 8 lanes over
          if (n < 8){
            int b = mt*16 + (lane >> 4)*4 + r;
            int d = d0 + n;
            float hp = (float)(((const _Float16*)smem)[16384 + b*512 + (d ^ ((b&7)<<3))]);
            float s0 = hp + sigmf(acc[r]) * (tanhf(other) - hp);
            cstore1(&S0[b*512 + d], s0);
          }
        }
      }
      drain();
      __syncthreads();
      if (tid == 0) bump(ready + 0);
    }
    // final h (step 63 results live in hacc[1])
    waitge(ready + 7*32, 112*64);
    for (int e4 = tid; e4 < 4096; e4 += 256){
      int b = e4 >> 7, d = (e4 & 127)*4;
      float2 u = cload2(&hacc[16384 + b*512 + d]);
      float2 v = cload2(&hacc[16384 + b*512 + d + 2]);
      float4 h4; h4.x = u.x; h4.y = u.y; h4.z = v.x; h4.w = v.y;
      if ((d >> 3) != blk) continue;
      ((float4*)outLH)[e4] = h4;
      half4v hv; hv[0]=(_Float16)h4.x; hv[1]=(_Float16)h4.y; hv[2]=(_Float16)h4.z; hv[3]=(_Float16)h4.w;
      *(half4v*)&A16[(size_t)(2016 + b)*512 + d] = hv;
    }
  } else {
    // ================= edge blocks =================
    const float invi = (in_ > 0) ? 1.f/(float)in_ : 1.f;
    const int actc = ACTC[jn];
    const float hscale = 1.f/(7.f*(float)jn);
    const int mt = wv >> 1, ch = wv & 1;
    const int bidx = mt*16 + (lane & 15);
    const int nc = ch*16 + (lane & 15);
    const int nh = nc + 32;
    const int d = d0 + ch*16 + (lane & 15);
    for (int t = 0; t < 64; ++t){
      if (in_ == 0) waitge(ready + 0, 64*(t+1));
      else { waitge(initc + jn*32, 16*(t+1)); waitge(ready + in_*32, 16*in_*(t+1)); }
      const float* A  = sumb + (t&1)*131072 + in_*16384;
      float* SJ = sumb + (t&1)*131072 + jn*16384;
      float* HA = hacc + (t&1)*16384;
      if (ei == 6){  // (0,7) set: zero next-parity hacc (off critical path; ordered before its ready[7] bump)
        float* hz = hacc + ((t+1)&1)*16384;
        int base = q*1024;
        #pragma unroll
        for (int z = 0; z < 2; ++z) cstore2(&hz[base + (tid*2 + z*512)], 0.f, 0.f);
      }
      float sp[4];
      #pragma unroll
      for (int r = 0; r < 4; ++r){
        int b = mt*16 + (lane >> 4)*4 + r;
        sp[r] = cload1(&A[b*512 + d]);
      }
      f32x4 accc = {0.f,0.f,0.f,0.f}, acch = {0.f,0.f,0.f,0.f};
      for (int kk = 0; kk < 16; ++kk){
        int kc = kk*32 + (lane >> 4)*8;
        float2 a0 = cload2(&A[bidx*512 + kc]);
        float2 a1 = cload2(&A[bidx*512 + kc + 2]);
        float2 a2 = cload2(&A[bidx*512 + kc + 4]);
        float2 a3 = cload2(&A[bidx*512 + kc + 6]);
        half8 af;
        af[0]=(_Float16)a0.x; af[1]=(_Float16)a0.y; af[2]=(_Float16)a1.x; af[3]=(_Float16)a1.y;
        af[4]=(_Float16)a2.x; af[5]=(_Float16)a2.y; af[6]=(_Float16)a3.x; af[7]=(_Float16)a3.y;
        half8 bc = *(const half8*)&smem[nc*512 + (kc ^ ((nc&7)<<3))];
        half8 bh = *(const half8*)&smem[nh*512 + (kc ^ ((nh&7)<<3))];
        accc = __builtin_amdgcn_mfma_f32_16x16x32_f16(af, bc, accc, 0, 0, 0);
        acch = __builtin_amdgcn_mfma_f32_16x16x32_f16(af, bh, acch, 0, 0, 0);
      }
      #pragma unroll
      for (int r = 0; r < 4; ++r){
        int b = mt*16 + (lane >> 4)*4 + r;
        float spv = sp[r] * invi;
        float hh = acch[r];
        float a = (actc==1) ? tanhf(hh) : (actc==2) ? fmaxf(hh,0.f) : (actc==3) ? sigmf(hh) : hh;
        float s = spv + sigmf(accc[r]) * (a - spv);
        if (in_ == 0) cstore1(&SJ[b*512 + d], s);
        else          cadd(&SJ[b*512 + d], s);
        cadd(&HA[b*512 + d], s * hscale);
      }
      drain();
      __syncthreads();
      if (tid == 0){
        bump(ready + jn*32);
        if (in_ == 0) bump(initc + jn*32);
      }
    }
  }
}

// ---------------- decoder GEMM: out[m,n] = sum_k A[m,k]*Bt[n,k] + bias[n], fp16 MFMA ----
__global__ __launch_bounds__(256) void k_gemm(const _Float16* __restrict__ A,
                                              const _Float16* __restrict__ Bt,
                                              const float* __restrict__ bias,
                                              float* __restrict__ out){
  __shared__ __align__(16) unsigned short A_lds[128*72];
  __shared__ __align__(16) unsigned short B_lds[128*72];
  int tid = threadIdx.x;
  int n0 = blockIdx.x * 128, m0 = blockIdx.y * 128;
  int lane = tid & 63, wvv = tid >> 6, wr = wvv >> 1, wc = wvv & 1;
  f32x4 acc[4][4];
  #pragma unroll
  for (int a = 0; a < 4; ++a)
    #pragma unroll
    for (int bq = 0; bq < 4; ++bq) acc[a][bq] = (f32x4){0.f,0.f,0.f,0.f};

  for (int k0 = 0; k0 < 512; k0 += 64){
    #pragma unroll
    for (int it = 0; it < 4; ++it){
      int c = tid + it*256; int row = c >> 3, c8 = c & 7;
      *(int4*)&A_lds[row*72 + c8*8] = *(const int4*)&A[(size_t)(m0+row)*512 + k0 + c8*8];
      *(int4*)&B_lds[row*72 + c8*8] = *(const int4*)&Bt[(size_t)(n0+row)*512 + k0 + c8*8];
    }
    __syncthreads();
    #pragma unroll
    for (int kk = 0; kk < 64; kk += 32){
      half8 av[4], bv[4];
      #pragma unroll
      for (int f = 0; f < 4; ++f){
        av[f] = *(const half8*)&A_lds[(wr*64 + f*16 + (lane&15))*72 + kk + (lane>>4)*8];
        bv[f] = *(const half8*)&B_lds[(wc*64 + f*16 + (lane&15))*72 + kk + (lane>>4)*8];
      }
      #pragma unroll
      for (int fm = 0; fm < 4; ++fm)
        #pragma unroll
        for (int fn = 0; fn < 4; ++fn)
          acc[fm][fn] = __builtin_amdgcn_mfma_f32_16x16x32_f16(av[fm], bv[fn], acc[fm][fn], 0, 0, 0);
    }
    __syncthreads();
  }
  #pragma unroll
  for (int fm = 0; fm < 4; ++fm){
    int mbase = m0 + wr*64 + fm*16 + ((lane>>4)<<2);
    #pragma unroll
    for (int fn = 0; fn < 4; ++fn){
      int n = n0 + wc*64 + fn*16 + (lane & 15);
      float bs = bias[n];
      #pragma unroll
      for (int r = 0; r < 4; ++r)
        out[(size_t)(mbase+r)*NTOK + n] = acc[fm][fn][r] + bs;
    }
  }
}

// ---------------- online log_softmax per row of 32000 (2 reads + 1 write) -------------
__global__ __launch_bounds__(256) void k_lsm(float* __restrict__ out){
  __shared__ float redm[8], reds[8];
  int row = blockIdx.x, tid = threadIdx.x;
  float* p = out + (size_t)row * NTOK;
  float4* p4 = (float4*)p;
  float m = -INFINITY, s = 0.f;
  for (int i = tid; i < 8000; i += 256){
    float4 v = p4[i];
    float vm = fmaxf(fmaxf(v.x,v.y), fmaxf(v.z,v.w));
    if (vm > m){ s *= __expf(m - vm); m = vm; }
    s += __expf(v.x-m)+__expf(v.y-m)+__expf(v.z-m)+__expf(v.w-m);
  }
  #pragma unroll
  for (int off = 32; off > 0; off >>= 1){
    float om = __shfl_down(m, off, 64);
    float os = __shfl_down(s, off, 64);
    float nm = fmaxf(m, om);
    s = s*__expf(m-nm) + os*__expf(om-nm);
    m = nm;
  }
  int wv = tid >> 6;
  if ((tid & 63) == 0){ redm[wv] = m; reds[wv] = s; }
  __syncthreads();
  if (tid == 0){
    m = redm[0]; s = reds[0];
    for (int w = 1; w < 4; ++w){
      float om = redm[w], os = reds[w];
      float nm = fmaxf(m, om);
      s = s*__expf(m-nm) + os*__expf(om-nm);
      m = nm;
    }
    redm[0] = m; reds[0] = logf(s);
  }
  __syncthreads();
  float L = redm[0] + reds[0];
  for (int i = tid; i < 8000; i += 256){
    float4 v = p4[i];
    v.x -= L; v.y -= L; v.z -= L; v.w -= L;
    p4[i] = v;
  }
}

extern "C" void kernel_launch(void* const* d_in, const int* in_sizes, int n_in,
                              void* d_out, int out_size, void* d_ws, size_t ws_size,
                              hipStream_t stream) {
  const int*   ids   = (const int*)  d_in[0];
  const float* h0f   = (const float*)d_in[1];
  const float* tab   = (const float*)d_in[2];
  const float* W0g   = (const float*)d_in[3];
  const float* Wsg   = (const float*)d_in[4];
  const float* bias  = (const float*)d_in[5];
  float* out = (float*)d_out;

  char* w = (char*)d_ws;
  int*       ctl   = (int*)w;                                  // 32 KB (memset 0)
  float*     hacc  = (float*)(w + 32768);                      // 128 KB (memset 0)
  float*     sumb  = (float*)(w + 32768 + 131072);             // 1 MB (2 x 8 x 16384 f)
  _Float16*  emb16 = (_Float16*)(w + 32768 + 131072 + 1048576);          // 2 MB
  _Float16*  A16   = (_Float16*)((char*)emb16 + 2097152);                // 2 MB
  _Float16*  T16   = (_Float16*)((char*)A16 + 2097152);                  // 32 MB

  hipMemsetAsync(ctl, 0, 32768 + 131072, stream);
  k_scan<<<512, 256, 0, stream>>>(ids, h0f, tab, W0g, Wsg, ctl, hacc, sumb,
                                  emb16, A16, T16, out + (size_t)2048*NTOK);
  k_gemm<<<dim3(250,16), 256, 0, stream>>>(A16, T16, bias, out);
  k_lsm<<<2048, 256, 0, stream>>>(out);
}